// Round 1
// baseline (672.826 us; speedup 1.0000x reference)
//
#include <hip/hip_runtime.h>
#include <stdint.h>

// Problem constants (B=4, N=2048, D=384, heads=6, hd=64)
#define NB 4
#define NN 2048
#define ND 384
#define NH 6
#define HD 64
#define ROWS (NB * NN)  // 8192

#if defined(__has_builtin)
#if __has_builtin(__builtin_amdgcn_sdot4)
#define HAVE_SDOT4 1
#endif
#endif

__device__ __forceinline__ int dot4i8(int a, int b, int c) {
#ifdef HAVE_SDOT4
    return __builtin_amdgcn_sdot4(a, b, c, false);
#else
    c += (int)(int8_t)(a & 0xFF) * (int)(int8_t)(b & 0xFF);
    c += (int)(int8_t)((a >> 8) & 0xFF) * (int)(int8_t)((b >> 8) & 0xFF);
    c += (int)(int8_t)((a >> 16) & 0xFF) * (int)(int8_t)((b >> 16) & 0xFF);
    c += (int)(int8_t)((a >> 24) & 0xFF) * (int)(int8_t)((b >> 24) & 0xFF);
    return c;
#endif
}

// ---------------------------------------------------------------------------
// Kernel 1: fused QKV projection. C[r, j] = x[r,:] . W[j,:] (i.e. x @ W^T),
// requantize *64, store int8 into [b, h, n, hd] layout.
// Grid: (ROWS/64, 18). blockIdx.y selects which of {wq,wk,wv} (6 col-blocks each).
// ---------------------------------------------------------------------------
__global__ __launch_bounds__(256) void qkv_gemm_kernel(
    const float* __restrict__ X,
    const float* __restrict__ Wq, const float* __restrict__ Wk, const float* __restrict__ Wv,
    const float* __restrict__ Bq, const float* __restrict__ Bk, const float* __restrict__ Bv,
    int8_t* __restrict__ Q8, int8_t* __restrict__ K8, int8_t* __restrict__ V8)
{
    __shared__ float As[16][68];  // [BK][BM+4] pad keeps 16B alignment, breaks conflicts
    __shared__ float Bs[16][68];

    const int t = threadIdx.x;
    const int row0 = blockIdx.x * 64;
    const int jb = blockIdx.y;          // 0..17
    const int m = jb / 6;               // 0=Q 1=K 2=V
    const int c0 = (jb % 6) * 64;       // column offset within the 384-col matrix
    const float* W = (m == 0) ? Wq : (m == 1) ? Wk : Wv;
    const float* Bi = (m == 0) ? Bq : (m == 1) ? Bk : Bv;
    int8_t* Out = (m == 0) ? Q8 : (m == 1) ? K8 : V8;

    const int li = t >> 2;              // 0..63
    const int lk = (t & 3) << 2;        // 0,4,8,12
    const int tx = t & 15, ty = t >> 4;

    float acc[4][4] = {{0.f}};

    for (int k0 = 0; k0 < ND; k0 += 16) {
        float4 a = *(const float4*)&X[(size_t)(row0 + li) * ND + k0 + lk];
        float4 b = *(const float4*)&W[(size_t)(c0 + li) * ND + k0 + lk];
        As[lk + 0][li] = a.x; As[lk + 1][li] = a.y; As[lk + 2][li] = a.z; As[lk + 3][li] = a.w;
        Bs[lk + 0][li] = b.x; Bs[lk + 1][li] = b.y; Bs[lk + 2][li] = b.z; Bs[lk + 3][li] = b.w;
        __syncthreads();
#pragma unroll
        for (int kk = 0; kk < 16; kk++) {
            float4 av = *(const float4*)&As[kk][ty * 4];
            float4 bv = *(const float4*)&Bs[kk][tx * 4];
            float aa[4] = {av.x, av.y, av.z, av.w};
            float bb[4] = {bv.x, bv.y, bv.z, bv.w};
#pragma unroll
            for (int i = 0; i < 4; i++)
#pragma unroll
                for (int j = 0; j < 4; j++)
                    acc[i][j] += aa[i] * bb[j];
        }
        __syncthreads();
    }

#pragma unroll
    for (int i = 0; i < 4; i++) {
        const int r = row0 + ty * 4 + i;
        const int bidx = r >> 11;       // / 2048
        const int n = r & 2047;
#pragma unroll
        for (int j = 0; j < 4; j++) {
            const int c = c0 + tx * 4 + j;
            float v = acc[i][j] + Bi[c];
            int qv = (int)floorf(v * 64.0f);   // mult=16384, shift=8 -> *64 exact
            qv = max(-128, min(127, qv));
            const int head = c >> 6, dim = c & 63;
            Out[(((size_t)(bidx * NH + head) * NN) + n) * HD + dim] = (int8_t)qv;
        }
    }
}

// ---------------------------------------------------------------------------
// Kernel 2: one block (256 thr) per (b, h, q) row.
// Phase A: 2048 logits via int8 dot4, requant (*5 >> 12), clamp.
// Phase B: exact ITA streaming softmax (128 chunks of 16, sequential E recurrence).
// Phase C: ctx[d] = sum_k attn[k] * V[k][d], >> 8, clamp, store int8 [b,n,h*64+d].
// ---------------------------------------------------------------------------
__global__ __launch_bounds__(256) void attn_kernel(
    const int8_t* __restrict__ Q8, const int8_t* __restrict__ K8,
    const int8_t* __restrict__ V8, int8_t* __restrict__ CTX8)
{
    __shared__ int qpack[16];
    __shared__ int8_t sl[2048];         // logits, then attn (u8) in place
    __shared__ int cmax[128];
    __shared__ int cesum[128];
    __shared__ int partial[16][64];
    __shared__ int fin[2];

    const int t = threadIdx.x;
    const int bhq = blockIdx.x;
    const int q = bhq & (NN - 1);
    const int bh = bhq >> 11;           // 0..23
    const size_t base = (size_t)bh * NN * HD;

    if (t < 16) qpack[t] = ((const int*)(Q8 + base + (size_t)q * HD))[t];
    __syncthreads();
    int qp[16];
#pragma unroll
    for (int j = 0; j < 16; j++) qp[j] = qpack[j];

    // ---- Phase A: logits ----
#pragma unroll
    for (int i = 0; i < 8; i++) {
        const int k = t + i * 256;
        const int4* Kr = (const int4*)(K8 + base + (size_t)k * HD);
        int4 p0 = Kr[0], p1 = Kr[1], p2 = Kr[2], p3 = Kr[3];
        int s = 0;
        s = dot4i8(qp[0],  p0.x, s); s = dot4i8(qp[1],  p0.y, s);
        s = dot4i8(qp[2],  p0.z, s); s = dot4i8(qp[3],  p0.w, s);
        s = dot4i8(qp[4],  p1.x, s); s = dot4i8(qp[5],  p1.y, s);
        s = dot4i8(qp[6],  p1.z, s); s = dot4i8(qp[7],  p1.w, s);
        s = dot4i8(qp[8],  p2.x, s); s = dot4i8(qp[9],  p2.y, s);
        s = dot4i8(qp[10], p2.z, s); s = dot4i8(qp[11], p2.w, s);
        s = dot4i8(qp[12], p3.x, s); s = dot4i8(qp[13], p3.y, s);
        s = dot4i8(qp[14], p3.z, s); s = dot4i8(qp[15], p3.w, s);
        int lg = (s * 5) >> 12;         // MA=5, SA=12; arithmetic shift == floor
        lg = max(-128, min(127, lg));
        sl[k] = (int8_t)lg;
    }
    __syncthreads();

    // ---- Phase B: ITA softmax ----
    if (t < 128) {                      // per-chunk max
        int m = -128;
        const int8_t* p = &sl[t * 16];
#pragma unroll
        for (int j = 0; j < 16; j++) m = max(m, (int)p[j]);
        cmax[t] = m;
    }
    __syncthreads();
    if (t == 0) {                       // prefix max (running global max M_g)
        int m = -128;
        for (int g = 0; g < 128; g++) { m = max(m, cmax[g]); cmax[g] = m; }
    }
    __syncthreads();
    if (t < 128) {                      // chunk exp-sum vs running max
        const int M = cmax[t];
        const int8_t* p = &sl[t * 16];
        int s = 0;
#pragma unroll
        for (int j = 0; j < 16; j++) {
            const int sh = M - (int)p[j];
            s += (sh < 32) ? (256 >> sh) : 0;
        }
        cesum[t] = s;
    }
    __syncthreads();
    if (t == 0) {                       // sequential E recurrence (order matters)
        int E = 0, Mp = -128;
        for (int g = 0; g < 128; g++) {
            int d = cmax[g] - Mp; if (d > 31) d = 31;
            E = (E >> d) + cesum[g];
            Mp = cmax[g];
        }
        fin[0] = Mp;                    // global max
        fin[1] = 65280 / E;             // E >= 256 always, inv <= 255
    }
    __syncthreads();
    const int gmax = fin[0], inv = fin[1];

    uint8_t* attn = (uint8_t*)sl;       // overwrite logits in place (same index/thread)
#pragma unroll
    for (int i = 0; i < 8; i++) {
        const int k = t + i * 256;
        const int sh = gmax - (int)sl[k];
        attn[k] = (uint8_t)((sh < 32) ? (inv >> sh) : 0);
    }
    __syncthreads();

    // ---- Phase C: ctx = attn . V ----
    const int dg = t & 15;              // dim group: dims 4*dg .. 4*dg+3
    const int kg = t >> 4;              // key group 0..15
    int a0 = 0, a1 = 0, a2 = 0, a3 = 0;
    for (int k = kg; k < NN; k += 16) {
        const int a = attn[k];
        if (a) {                        // most attn weights are 0 (shift >= 8)
            const int v = ((const int*)(V8 + base + (size_t)k * HD))[dg];
            a0 += a * (int)(int8_t)(v & 0xFF);
            a1 += a * (int)(int8_t)((v >> 8) & 0xFF);
            a2 += a * (int)(int8_t)((v >> 16) & 0xFF);
            a3 += a * (int)(int8_t)((v >> 24) & 0xFF);
        }
    }
    partial[kg][dg * 4 + 0] = a0;
    partial[kg][dg * 4 + 1] = a1;
    partial[kg][dg * 4 + 2] = a2;
    partial[kg][dg * 4 + 3] = a3;
    __syncthreads();
    if (t < 64) {
        int s = 0;
#pragma unroll
        for (int g = 0; g < 16; g++) s += partial[g][t];
        int c = s >> 8;                 // MAV=1, SAV=8: floor div
        c = max(-128, min(127, c));
        const int b = bh / NH, head = bh % NH;
        CTX8[((size_t)(b * NN + q)) * ND + head * HD + t] = (int8_t)c;
    }
}

// ---------------------------------------------------------------------------
// Kernel 3: out = requantize(ctx @ wo^T + bo, 256, 7)  -> floor(v*2), clamp, fp32
// ---------------------------------------------------------------------------
__global__ __launch_bounds__(256) void out_gemm_kernel(
    const int8_t* __restrict__ CTX8, const float* __restrict__ Wo,
    const float* __restrict__ Bo, float* __restrict__ out)
{
    __shared__ float As[16][68];
    __shared__ float Bs[16][68];

    const int t = threadIdx.x;
    const int row0 = blockIdx.x * 64;
    const int c0 = blockIdx.y * 64;
    const int li = t >> 2;
    const int lk = (t & 3) << 2;
    const int tx = t & 15, ty = t >> 4;

    float acc[4][4] = {{0.f}};

    for (int k0 = 0; k0 < ND; k0 += 16) {
        const int av = *(const int*)&CTX8[(size_t)(row0 + li) * ND + k0 + lk];
        float4 b = *(const float4*)&Wo[(size_t)(c0 + li) * ND + k0 + lk];
        As[lk + 0][li] = (float)(int)(int8_t)(av & 0xFF);
        As[lk + 1][li] = (float)(int)(int8_t)((av >> 8) & 0xFF);
        As[lk + 2][li] = (float)(int)(int8_t)((av >> 16) & 0xFF);
        As[lk + 3][li] = (float)(int)(int8_t)((av >> 24) & 0xFF);
        Bs[lk + 0][li] = b.x; Bs[lk + 1][li] = b.y; Bs[lk + 2][li] = b.z; Bs[lk + 3][li] = b.w;
        __syncthreads();
#pragma unroll
        for (int kk = 0; kk < 16; kk++) {
            float4 avv = *(const float4*)&As[kk][ty * 4];
            float4 bvv = *(const float4*)&Bs[kk][tx * 4];
            float aa[4] = {avv.x, avv.y, avv.z, avv.w};
            float bb[4] = {bvv.x, bvv.y, bvv.z, bvv.w};
#pragma unroll
            for (int i = 0; i < 4; i++)
#pragma unroll
                for (int j = 0; j < 4; j++)
                    acc[i][j] += aa[i] * bb[j];
        }
        __syncthreads();
    }

#pragma unroll
    for (int i = 0; i < 4; i++) {
        const int r = row0 + ty * 4 + i;
#pragma unroll
        for (int j = 0; j < 4; j++) {
            const int c = c0 + tx * 4 + j;
            float v = acc[i][j] + Bo[c];
            float rq = floorf(v * 2.0f);        // mult=256, shift=7 -> *2 exact
            rq = fminf(fmaxf(rq, -128.0f), 127.0f);
            out[(size_t)r * ND + c] = rq;
        }
    }
}

extern "C" void kernel_launch(void* const* d_in, const int* in_sizes, int n_in,
                              void* d_out, int out_size, void* d_ws, size_t ws_size,
                              hipStream_t stream)
{
    const float* x  = (const float*)d_in[0];
    const float* wq = (const float*)d_in[1];
    const float* bq = (const float*)d_in[2];
    const float* wk = (const float*)d_in[3];
    const float* bk = (const float*)d_in[4];
    const float* wv = (const float*)d_in[5];
    const float* bv = (const float*)d_in[6];
    const float* wo = (const float*)d_in[7];
    const float* bo = (const float*)d_in[8];
    float* out = (float*)d_out;

    const size_t MAT = (size_t)ROWS * ND;   // 3,145,728 bytes each
    int8_t* Q8 = (int8_t*)d_ws;
    int8_t* K8 = Q8 + MAT;
    int8_t* V8 = K8 + MAT;
    int8_t* C8 = V8 + MAT;

    qkv_gemm_kernel<<<dim3(ROWS / 64, 18), 256, 0, stream>>>(
        x, wq, wk, wv, bq, bk, bv, Q8, K8, V8);
    attn_kernel<<<dim3(NB * NH * NN), 256, 0, stream>>>(Q8, K8, V8, C8);
    out_gemm_kernel<<<dim3(ROWS / 64, ND / 64), 256, 0, stream>>>(C8, wo, bo, out);
}

// Round 2
// 407.207 us; speedup vs baseline: 1.6523x; 1.6523x over previous
//
#include <hip/hip_runtime.h>
#include <stdint.h>

// Problem constants (B=4, N=2048, D=384, heads=6, hd=64)
#define NB 4
#define NN 2048
#define ND 384
#define NH 6
#define HD 64
#define ROWS (NB * NN)  // 8192

typedef int v4i __attribute__((ext_vector_type(4)));

#if defined(__has_builtin)
#if __has_builtin(__builtin_amdgcn_sdot4)
#define HAVE_SDOT4 1
#endif
#endif

__device__ __forceinline__ int dot4i8(int a, int b, int c) {
#ifdef HAVE_SDOT4
    return __builtin_amdgcn_sdot4(a, b, c, false);
#else
    c += (int)(int8_t)(a & 0xFF) * (int)(int8_t)(b & 0xFF);
    c += (int)(int8_t)((a >> 8) & 0xFF) * (int)(int8_t)((b >> 8) & 0xFF);
    c += (int)(int8_t)((a >> 16) & 0xFF) * (int)(int8_t)((b >> 16) & 0xFF);
    c += (int)(int8_t)((a >> 24) & 0xFF) * (int)(int8_t)((b >> 24) & 0xFF);
    return c;
#endif
}

// ---------------------------------------------------------------------------
// Kernel 1: fused QKV projection. Q/K stored [bh][n][64] i8; V stored
// TRANSPOSED [bh][d][n] i8 (packed u32 stores) for MFMA B-fragments.
// ---------------------------------------------------------------------------
__global__ __launch_bounds__(256) void qkv_gemm_kernel(
    const float* __restrict__ X,
    const float* __restrict__ Wq, const float* __restrict__ Wk, const float* __restrict__ Wv,
    const float* __restrict__ Bq, const float* __restrict__ Bk, const float* __restrict__ Bv,
    int8_t* __restrict__ Q8, int8_t* __restrict__ K8, int8_t* __restrict__ V8T)
{
    __shared__ float As[16][68];
    __shared__ float Bs[16][68];

    const int t = threadIdx.x;
    const int row0 = blockIdx.x * 64;
    const int jb = blockIdx.y;          // 0..17
    const int m = jb / 6;               // 0=Q 1=K 2=V
    const int c0 = (jb % 6) * 64;
    const float* W = (m == 0) ? Wq : (m == 1) ? Wk : Wv;
    const float* Bi = (m == 0) ? Bq : (m == 1) ? Bk : Bv;

    const int li = t >> 2;
    const int lk = (t & 3) << 2;
    const int tx = t & 15, ty = t >> 4;

    float acc[4][4] = {{0.f}};

    for (int k0 = 0; k0 < ND; k0 += 16) {
        float4 a = *(const float4*)&X[(size_t)(row0 + li) * ND + k0 + lk];
        float4 b = *(const float4*)&W[(size_t)(c0 + li) * ND + k0 + lk];
        As[lk + 0][li] = a.x; As[lk + 1][li] = a.y; As[lk + 2][li] = a.z; As[lk + 3][li] = a.w;
        Bs[lk + 0][li] = b.x; Bs[lk + 1][li] = b.y; Bs[lk + 2][li] = b.z; Bs[lk + 3][li] = b.w;
        __syncthreads();
#pragma unroll
        for (int kk = 0; kk < 16; kk++) {
            float4 av = *(const float4*)&As[kk][ty * 4];
            float4 bv = *(const float4*)&Bs[kk][tx * 4];
            float aa[4] = {av.x, av.y, av.z, av.w};
            float bb[4] = {bv.x, bv.y, bv.z, bv.w};
#pragma unroll
            for (int i = 0; i < 4; i++)
#pragma unroll
                for (int j = 0; j < 4; j++)
                    acc[i][j] += aa[i] * bb[j];
        }
        __syncthreads();
    }

    if (m == 2) {
        // V transposed: pack 4 consecutive-n bytes -> one u32 per dim
        const int r0 = row0 + ty * 4;
        const int bidx = r0 >> 11;
        const int n0 = r0 & 2047;
#pragma unroll
        for (int j = 0; j < 4; j++) {
            const int c = c0 + tx * 4 + j;
            const int head = c >> 6, dim = c & 63;
            uint32_t w = 0;
#pragma unroll
            for (int i = 0; i < 4; i++) {
                float v = acc[i][j] + Bi[c];
                int qv = (int)floorf(v * 64.0f);
                qv = max(-128, min(127, qv));
                w |= (uint32_t)(qv & 255) << (8 * i);
            }
            *(uint32_t*)(V8T + (((size_t)(bidx * NH + head) * HD + dim) * NN + n0)) = w;
        }
    } else {
        int8_t* Out = (m == 0) ? Q8 : K8;
#pragma unroll
        for (int i = 0; i < 4; i++) {
            const int r = row0 + ty * 4 + i;
            const int bidx = r >> 11;
            const int n = r & 2047;
#pragma unroll
            for (int j = 0; j < 4; j++) {
                const int c = c0 + tx * 4 + j;
                float v = acc[i][j] + Bi[c];
                int qv = (int)floorf(v * 64.0f);
                qv = max(-128, min(127, qv));
                const int head = c >> 6, dim = c & 63;
                Out[(((size_t)(bidx * NH + head) * NN) + n) * HD + dim] = (int8_t)qv;
            }
        }
    }
}

// ---------------------------------------------------------------------------
// Kernel 1b: colsum of V per (bh, d) over all 2048 keys (for the a-128 trick)
// ---------------------------------------------------------------------------
__global__ __launch_bounds__(256) void colsum_kernel(
    const int8_t* __restrict__ V8T, int* __restrict__ colsum)
{
    __shared__ int part[256];
    const int bh = blockIdx.x;
    const int t = threadIdx.x;
    const int d = t >> 2, pp = t & 3;
    const int* p = (const int*)(V8T + (size_t)bh * NN * HD + (size_t)d * NN + pp * 512);
    int s = 0;
#pragma unroll 4
    for (int i = 0; i < 128; ++i) s = dot4i8(p[i], 0x01010101, s);
    part[t] = s;
    __syncthreads();
    if (pp == 0) colsum[bh * 64 + d] = part[t] + part[t + 1] + part[t + 2] + part[t + 3];
}

// ---------------------------------------------------------------------------
// Kernel 2: MFMA attention. One wave (64 thr) per 16-query strip.
// Phase A: 128x  mfma_i32_16x16x64_i8 -> logits, packed C-layout words in LDS.
// Phase B: exact ITA softmax stats (group max, prefix max, esum, E recurrence).
// Phase C: attn(-128) . V via MFMA, a-frags assembled from LDS with the
//          attn transform folded in; +128*colsum correction in epilogue.
// ---------------------------------------------------------------------------
__global__ __launch_bounds__(64) void attn_kernel(
    const int8_t* __restrict__ Q8, const int8_t* __restrict__ K8,
    const int8_t* __restrict__ V8T, const int* __restrict__ colsum,
    int8_t* __restrict__ CTX8)
{
    // Packed logits: word [g][ (q>>2)*16 + k15 ], byte (q&3). Group stride 68
    // words (pad 4) -> conflict-free writes, 2-way/broadcast transposed reads.
    __shared__ int Lp[128 * 68];        // 34816 B
    __shared__ int gmaxp[16 * 132];     // prefix maxes, padded stride
    __shared__ int esum[16 * 132];
    __shared__ int invq[16];
    __shared__ int gmq[16];

    const int lane = threadIdx.x;
    const int quad = lane >> 4;
    const int l15 = lane & 15;
    const int bh = blockIdx.y;
    const int q0 = blockIdx.x * 16;
    const size_t base = (size_t)bh * NN * HD;

    // ---- Phase A: logits via MFMA ----
    const v4i zero = {0, 0, 0, 0};
    v4i afrag = *(const v4i*)(Q8 + base + (size_t)(q0 + l15) * HD + quad * 16);
    for (int kt = 0; kt < 128; ++kt) {
        v4i bfrag = *(const v4i*)(K8 + base + (size_t)(kt * 16 + l15) * HD + quad * 16);
        v4i d = __builtin_amdgcn_mfma_i32_16x16x64_i8(afrag, bfrag, zero, 0, 0, 0);
        int w = 0;
#pragma unroll
        for (int r = 0; r < 4; ++r) {
            int lg = (d[r] * 5) >> 12;          // MA=5, SA=12, arith shr == floor
            lg = min(127, max(-128, lg));
            w |= (lg & 255) << (8 * r);
        }
        Lp[kt * 68 + quad * 16 + l15] = w;      // D: col=lane&15(key), row=quad*4+r(q)
    }
    __syncthreads();

    // ---- Phase B1: per-(q,group) max (shift-to-MSB trick) ----
    const int qq = quad;
    for (int gi = 0; gi < 8; ++gi) {
        const int g = l15 + gi * 16;
        const int* p = &Lp[g * 68 + qq * 16];
        int wb[16];
#pragma unroll
        for (int a = 0; a < 4; ++a) {
            v4i v = *(const v4i*)&p[a * 4];
            wb[a * 4 + 0] = v.x; wb[a * 4 + 1] = v.y; wb[a * 4 + 2] = v.z; wb[a * 4 + 3] = v.w;
        }
#pragma unroll
        for (int b = 0; b < 4; ++b) {
            int mx = INT_MIN;
#pragma unroll
            for (int j = 0; j < 16; ++j)
                mx = max(mx, (int)((unsigned)wb[j] << (8 * (3 - b))));
            gmaxp[(qq * 4 + b) * 132 + g] = (mx >> 24);
        }
    }
    __syncthreads();

    // ---- Phase B2: prefix max per q row ----
    if (lane < 16) {
        int m = -128;
        for (int g4 = 0; g4 < 128; g4 += 4) {
            v4i v = *(v4i*)&gmaxp[lane * 132 + g4];
            m = max(m, v.x); v.x = m;
            m = max(m, v.y); v.y = m;
            m = max(m, v.z); v.z = m;
            m = max(m, v.w); v.w = m;
            *(v4i*)&gmaxp[lane * 132 + g4] = v;
        }
    }
    __syncthreads();

    // ---- Phase B3: per-group exp sums vs prefix max (exact: powers of 2) ----
    for (int gi = 0; gi < 8; ++gi) {
        const int g = l15 + gi * 16;
        const int* p = &Lp[g * 68 + qq * 16];
        int wb[16];
#pragma unroll
        for (int a = 0; a < 4; ++a) {
            v4i v = *(const v4i*)&p[a * 4];
            wb[a * 4 + 0] = v.x; wb[a * 4 + 1] = v.y; wb[a * 4 + 2] = v.z; wb[a * 4 + 3] = v.w;
        }
#pragma unroll
        for (int b = 0; b < 4; ++b) {
            const int M = gmaxp[(qq * 4 + b) * 132 + g];
            const int cb = 8 - M;                    // t = x - M + 8; e = t>=0 ? 1<<t : 0
            int s = 0;
#pragma unroll
            for (int j = 0; j < 16; ++j) {
                int x = (int)(int8_t)(wb[j] >> (8 * b));
                int tt = x + cb;                     // <= 8 always (x <= M)
                s += (tt >= 0) ? (1 << tt) : 0;
            }
            esum[(qq * 4 + b) * 132 + g] = s;
        }
    }
    __syncthreads();

    // ---- Phase B4: sequential E recurrence (order-dependent, exact) ----
    if (lane < 16) {
        int E = 0, Mp = -128;
        for (int g = 0; g < 128; ++g) {
            int m = gmaxp[lane * 132 + g];
            int d = m - Mp; if (d > 31) d = 31;
            E = (E >> d) + esum[lane * 132 + g];
            Mp = m;
        }
        invq[lane] = 65280 / E;                      // E >= 256 -> inv <= 255
        gmq[lane] = Mp;
    }
    __syncthreads();

    // ---- Phase C: ctx = (attn-128) . V via MFMA, transform folded in ----
    const int inv_l = invq[l15];                     // a-frag row m = lane&15 = q
    const int gm_l = gmq[l15];
    const int sh8 = 8 * (l15 & 3);
    const int wrow = (l15 >> 2) * 16;
    v4i accs[4] = {zero, zero, zero, zero};
    const int8_t* vtb = V8T + base;

    for (int kc = 0; kc < 32; ++kc) {
        const int* lp = &Lp[(kc * 4 + quad) * 68 + wrow];
        v4i a;
#pragma unroll
        for (int r = 0; r < 4; ++r) {
            int wreg = 0;
#pragma unroll
            for (int c = 0; c < 4; ++c) {
                int w = lp[4 * r + c];
                int x = (int)(int8_t)(w >> sh8);
                int sh = gm_l - x;                   // >= 0
                int shc = min(sh, 31);
                int aa = (sh <= 7) ? (inv_l >> shc) : 0;
                wreg |= ((aa - 128) & 255) << (8 * c);
            }
            a[r] = wreg;
        }
        const int koff = kc * 64 + quad * 16;
        v4i b0 = *(const v4i*)(vtb + (size_t)(0 * 16 + l15) * NN + koff);
        v4i b1 = *(const v4i*)(vtb + (size_t)(1 * 16 + l15) * NN + koff);
        v4i b2 = *(const v4i*)(vtb + (size_t)(2 * 16 + l15) * NN + koff);
        v4i b3 = *(const v4i*)(vtb + (size_t)(3 * 16 + l15) * NN + koff);
        accs[0] = __builtin_amdgcn_mfma_i32_16x16x64_i8(a, b0, accs[0], 0, 0, 0);
        accs[1] = __builtin_amdgcn_mfma_i32_16x16x64_i8(a, b1, accs[1], 0, 0, 0);
        accs[2] = __builtin_amdgcn_mfma_i32_16x16x64_i8(a, b2, accs[2], 0, 0, 0);
        accs[3] = __builtin_amdgcn_mfma_i32_16x16x64_i8(a, b3, accs[3], 0, 0, 0);
    }

    // ---- Epilogue: +128*colsum correction, >>8, clamp, store ----
    const int bb = bh / NH, hh = bh % NH;
    const int* cs = &colsum[bh * 64];
#pragma unroll
    for (int dt = 0; dt < 4; ++dt) {
        const int dcol = dt * 16 + l15;
        const int corr = cs[dcol] << 7;
#pragma unroll
        for (int r = 0; r < 4; ++r) {
            const int q = q0 + quad * 4 + r;
            int val = (accs[dt][r] + corr) >> 8;     // MAV=1, SAV=8 floor
            val = min(127, max(-128, val));
            CTX8[((size_t)(bb * NN + q)) * ND + hh * HD + dcol] = (int8_t)val;
        }
    }
}

// ---------------------------------------------------------------------------
// Kernel 3: out = requantize(ctx @ wo^T + bo, 256, 7) -> floor(v*2), clamp
// ---------------------------------------------------------------------------
__global__ __launch_bounds__(256) void out_gemm_kernel(
    const int8_t* __restrict__ CTX8, const float* __restrict__ Wo,
    const float* __restrict__ Bo, float* __restrict__ out)
{
    __shared__ float As[16][68];
    __shared__ float Bs[16][68];

    const int t = threadIdx.x;
    const int row0 = blockIdx.x * 64;
    const int c0 = blockIdx.y * 64;
    const int li = t >> 2;
    const int lk = (t & 3) << 2;
    const int tx = t & 15, ty = t >> 4;

    float acc[4][4] = {{0.f}};

    for (int k0 = 0; k0 < ND; k0 += 16) {
        const int av = *(const int*)&CTX8[(size_t)(row0 + li) * ND + k0 + lk];
        float4 b = *(const float4*)&Wo[(size_t)(c0 + li) * ND + k0 + lk];
        As[lk + 0][li] = (float)(int)(int8_t)(av & 0xFF);
        As[lk + 1][li] = (float)(int)(int8_t)((av >> 8) & 0xFF);
        As[lk + 2][li] = (float)(int)(int8_t)((av >> 16) & 0xFF);
        As[lk + 3][li] = (float)(int)(int8_t)((av >> 24) & 0xFF);
        Bs[lk + 0][li] = b.x; Bs[lk + 1][li] = b.y; Bs[lk + 2][li] = b.z; Bs[lk + 3][li] = b.w;
        __syncthreads();
#pragma unroll
        for (int kk = 0; kk < 16; kk++) {
            float4 avv = *(const float4*)&As[kk][ty * 4];
            float4 bvv = *(const float4*)&Bs[kk][tx * 4];
            float aa[4] = {avv.x, avv.y, avv.z, avv.w};
            float bb[4] = {bvv.x, bvv.y, bvv.z, bvv.w};
#pragma unroll
            for (int i = 0; i < 4; i++)
#pragma unroll
                for (int j = 0; j < 4; j++)
                    acc[i][j] += aa[i] * bb[j];
        }
        __syncthreads();
    }

#pragma unroll
    for (int i = 0; i < 4; i++) {
        const int r = row0 + ty * 4 + i;
#pragma unroll
        for (int j = 0; j < 4; j++) {
            const int c = c0 + tx * 4 + j;
            float v = acc[i][j] + Bo[c];
            float rq = floorf(v * 2.0f);
            rq = fminf(fmaxf(rq, -128.0f), 127.0f);
            out[(size_t)r * ND + c] = rq;
        }
    }
}

extern "C" void kernel_launch(void* const* d_in, const int* in_sizes, int n_in,
                              void* d_out, int out_size, void* d_ws, size_t ws_size,
                              hipStream_t stream)
{
    const float* x  = (const float*)d_in[0];
    const float* wq = (const float*)d_in[1];
    const float* bq = (const float*)d_in[2];
    const float* wk = (const float*)d_in[3];
    const float* bk = (const float*)d_in[4];
    const float* wv = (const float*)d_in[5];
    const float* bv = (const float*)d_in[6];
    const float* wo = (const float*)d_in[7];
    const float* bo = (const float*)d_in[8];
    float* out = (float*)d_out;

    const size_t MAT = (size_t)ROWS * ND;   // 3,145,728 bytes each
    int8_t* Q8  = (int8_t*)d_ws;
    int8_t* K8  = Q8 + MAT;
    int8_t* V8T = K8 + MAT;
    int8_t* C8  = V8T + MAT;
    int*    CS  = (int*)(C8 + MAT);         // 24*64 ints

    qkv_gemm_kernel<<<dim3(ROWS / 64, 18), 256, 0, stream>>>(
        x, wq, wk, wv, bq, bk, bv, Q8, K8, V8T);
    colsum_kernel<<<dim3(NB * NH), 256, 0, stream>>>(V8T, CS);
    attn_kernel<<<dim3(NN / 16, NB * NH), 64, 0, stream>>>(Q8, K8, V8T, CS, C8);
    out_gemm_kernel<<<dim3(ROWS / 64, ND / 64), 256, 0, stream>>>(C8, wo, bo, out);
}

// Round 3
// 315.050 us; speedup vs baseline: 2.1356x; 1.2925x over previous
//
#include <hip/hip_runtime.h>
#include <stdint.h>

// Problem constants (B=4, N=2048, D=384, heads=6, hd=64)
#define NB 4
#define NN 2048
#define ND 384
#define NH 6
#define HD 64
#define ROWS (NB * NN)  // 8192

typedef int v4i __attribute__((ext_vector_type(4)));

#if defined(__has_builtin)
#if __has_builtin(__builtin_amdgcn_sdot4)
#define HAVE_SDOT4 1
#endif
#endif

__device__ __forceinline__ int dot4i8(int a, int b, int c) {
#ifdef HAVE_SDOT4
    return __builtin_amdgcn_sdot4(a, b, c, false);
#else
    c += (int)(int8_t)(a & 0xFF) * (int)(int8_t)(b & 0xFF);
    c += (int)(int8_t)((a >> 8) & 0xFF) * (int)(int8_t)((b >> 8) & 0xFF);
    c += (int)(int8_t)((a >> 16) & 0xFF) * (int)(int8_t)((b >> 16) & 0xFF);
    c += (int)(int8_t)((a >> 24) & 0xFF) * (int)(int8_t)((b >> 24) & 0xFF);
    return c;
#endif
}

// ---------------------------------------------------------------------------
// Kernel 1: fused QKV projection. Q/K stored [bh][n][64] i8; V stored
// TRANSPOSED [bh][d][n] i8 (packed u32 stores) for MFMA B-fragments.
// ---------------------------------------------------------------------------
__global__ __launch_bounds__(256) void qkv_gemm_kernel(
    const float* __restrict__ X,
    const float* __restrict__ Wq, const float* __restrict__ Wk, const float* __restrict__ Wv,
    const float* __restrict__ Bq, const float* __restrict__ Bk, const float* __restrict__ Bv,
    int8_t* __restrict__ Q8, int8_t* __restrict__ K8, int8_t* __restrict__ V8T)
{
    __shared__ float As[16][68];
    __shared__ float Bs[16][68];

    const int t = threadIdx.x;
    const int row0 = blockIdx.x * 64;
    const int jb = blockIdx.y;          // 0..17
    const int m = jb / 6;               // 0=Q 1=K 2=V
    const int c0 = (jb % 6) * 64;
    const float* W = (m == 0) ? Wq : (m == 1) ? Wk : Wv;
    const float* Bi = (m == 0) ? Bq : (m == 1) ? Bk : Bv;

    const int li = t >> 2;
    const int lk = (t & 3) << 2;
    const int tx = t & 15, ty = t >> 4;

    float acc[4][4] = {{0.f}};

    for (int k0 = 0; k0 < ND; k0 += 16) {
        float4 a = *(const float4*)&X[(size_t)(row0 + li) * ND + k0 + lk];
        float4 b = *(const float4*)&W[(size_t)(c0 + li) * ND + k0 + lk];
        As[lk + 0][li] = a.x; As[lk + 1][li] = a.y; As[lk + 2][li] = a.z; As[lk + 3][li] = a.w;
        Bs[lk + 0][li] = b.x; Bs[lk + 1][li] = b.y; Bs[lk + 2][li] = b.z; Bs[lk + 3][li] = b.w;
        __syncthreads();
#pragma unroll
        for (int kk = 0; kk < 16; kk++) {
            float4 av = *(const float4*)&As[kk][ty * 4];
            float4 bv = *(const float4*)&Bs[kk][tx * 4];
            float aa[4] = {av.x, av.y, av.z, av.w};
            float bb[4] = {bv.x, bv.y, bv.z, bv.w};
#pragma unroll
            for (int i = 0; i < 4; i++)
#pragma unroll
                for (int j = 0; j < 4; j++)
                    acc[i][j] += aa[i] * bb[j];
        }
        __syncthreads();
    }

    if (m == 2) {
        const int r0 = row0 + ty * 4;
        const int bidx = r0 >> 11;
        const int n0 = r0 & 2047;
#pragma unroll
        for (int j = 0; j < 4; j++) {
            const int c = c0 + tx * 4 + j;
            const int head = c >> 6, dim = c & 63;
            uint32_t w = 0;
#pragma unroll
            for (int i = 0; i < 4; i++) {
                float v = acc[i][j] + Bi[c];
                int qv = (int)floorf(v * 64.0f);
                qv = max(-128, min(127, qv));
                w |= (uint32_t)(qv & 255) << (8 * i);
            }
            *(uint32_t*)(V8T + (((size_t)(bidx * NH + head) * HD + dim) * NN + n0)) = w;
        }
    } else {
        int8_t* Out = (m == 0) ? Q8 : K8;
#pragma unroll
        for (int i = 0; i < 4; i++) {
            const int r = row0 + ty * 4 + i;
            const int bidx = r >> 11;
            const int n = r & 2047;
#pragma unroll
            for (int j = 0; j < 4; j++) {
                const int c = c0 + tx * 4 + j;
                float v = acc[i][j] + Bi[c];
                int qv = (int)floorf(v * 64.0f);
                qv = max(-128, min(127, qv));
                const int head = c >> 6, dim = c & 63;
                Out[(((size_t)(bidx * NH + head) * NN) + n) * HD + dim] = (int8_t)qv;
            }
        }
    }
}

// ---------------------------------------------------------------------------
// Kernel 1b: colsum of V per (bh, d) (for the attn-128 signed-MFMA trick)
// ---------------------------------------------------------------------------
__global__ __launch_bounds__(256) void colsum_kernel(
    const int8_t* __restrict__ V8T, int* __restrict__ colsum)
{
    __shared__ int part[256];
    const int bh = blockIdx.x;
    const int t = threadIdx.x;
    const int d = t >> 2, pp = t & 3;
    const int* p = (const int*)(V8T + (size_t)bh * NN * HD + (size_t)d * NN + pp * 512);
    int s = 0;
#pragma unroll 4
    for (int i = 0; i < 128; ++i) s = dot4i8(p[i], 0x01010101, s);
    part[t] = s;
    __syncthreads();
    if (pp == 0) colsum[bh * 64 + d] = part[t] + part[t + 1] + part[t + 2] + part[t + 3];
}

// ---------------------------------------------------------------------------
// Kernel 2: MFMA attention, 256 threads (4 waves) per 16-query strip.
//  A: waves split 128 k-tiles; QK MFMA -> packed logit words in LDS.
//  B: softmax stats parallelized across 256 threads; serial prefix/E on 16 lanes.
//  T: in-place logits -> (attn-128) bytes, each byte transformed once.
//  C: waves split 32 k-chunks; PV MFMA; cross-wave reduction via stats LDS.
// ---------------------------------------------------------------------------
__global__ __launch_bounds__(256, 3) void attn_kernel(
    const int8_t* __restrict__ Q8, const int8_t* __restrict__ K8,
    const int8_t* __restrict__ V8T, const int* __restrict__ colsum,
    int8_t* __restrict__ CTX8)
{
    // Packed logits: word [kt][qw*16 + k15], byte r <-> q=qw*4+r, k=kt*16+k15.
    __shared__ int Lp[128 * 68];        // 34816 B
    __shared__ int stats[2 * 16 * 132]; // gmax | esum; reused as reduction buffer
    __shared__ int invq[16];
    __shared__ int gmq[16];

    int* gmax = stats;                  // [16][132]
    int* esum = stats + 16 * 132;

    const int t = threadIdx.x;
    const int wid = t >> 6;
    const int lane = t & 63;
    const int quad = lane >> 4;
    const int l15 = lane & 15;
    const int bh = blockIdx.y;
    const int q0 = blockIdx.x * 16;
    const size_t base = (size_t)bh * NN * HD;
    const v4i zero = {0, 0, 0, 0};

    // ---- Phase A: logits via MFMA (waves split kt) ----
    v4i afrag = *(const v4i*)(Q8 + base + (size_t)(q0 + l15) * HD + quad * 16);
    for (int kt = wid * 32; kt < wid * 32 + 32; ++kt) {
        v4i bfrag = *(const v4i*)(K8 + base + (size_t)(kt * 16 + l15) * HD + quad * 16);
        v4i d = __builtin_amdgcn_mfma_i32_16x16x64_i8(afrag, bfrag, zero, 0, 0, 0);
        int w = 0;
#pragma unroll
        for (int r = 0; r < 4; ++r) {
            int lg = (d[r] * 5) >> 12;          // MA=5, SA=12: arith shr == floor
            lg = min(127, max(-128, lg));
            w |= (lg & 255) << (8 * r);
        }
        Lp[kt * 68 + quad * 16 + l15] = w;
    }
    __syncthreads();

    // ---- Phase B1: per-(q,group) max; 512 tasks over 256 threads ----
#pragma unroll
    for (int it = 0; it < 2; ++it) {
        const int task = t + it * 256;
        const int g = task & 127, qq = task >> 7;
        const int* p = &Lp[g * 68 + qq * 16];
        int wb[16];
#pragma unroll
        for (int a = 0; a < 4; ++a) {
            v4i v = *(const v4i*)&p[a * 4];
            wb[a * 4 + 0] = v.x; wb[a * 4 + 1] = v.y; wb[a * 4 + 2] = v.z; wb[a * 4 + 3] = v.w;
        }
#pragma unroll
        for (int b = 0; b < 4; ++b) {
            int mx = INT_MIN;
#pragma unroll
            for (int j = 0; j < 16; ++j)
                mx = max(mx, (int)((unsigned)wb[j] << (8 * (3 - b))));
            gmax[(qq * 4 + b) * 132 + g] = (mx >> 24);
        }
    }
    __syncthreads();

    // ---- Phase B2: prefix max per q row (wave 0, 16 lanes) ----
    if (t < 16) {
        int m = -128;
        for (int g4 = 0; g4 < 128; g4 += 4) {
            v4i v = *(v4i*)&gmax[t * 132 + g4];
            m = max(m, v.x); v.x = m;
            m = max(m, v.y); v.y = m;
            m = max(m, v.z); v.z = m;
            m = max(m, v.w); v.w = m;
            *(v4i*)&gmax[t * 132 + g4] = v;
        }
    }
    __syncthreads();

    // ---- Phase B3: per-group exp sums vs prefix max ----
#pragma unroll
    for (int it = 0; it < 2; ++it) {
        const int task = t + it * 256;
        const int g = task & 127, qq = task >> 7;
        const int* p = &Lp[g * 68 + qq * 16];
        int wb[16];
#pragma unroll
        for (int a = 0; a < 4; ++a) {
            v4i v = *(const v4i*)&p[a * 4];
            wb[a * 4 + 0] = v.x; wb[a * 4 + 1] = v.y; wb[a * 4 + 2] = v.z; wb[a * 4 + 3] = v.w;
        }
#pragma unroll
        for (int b = 0; b < 4; ++b) {
            const int M = gmax[(qq * 4 + b) * 132 + g];
            const int cb = 8 - M;
            int s = 0;
#pragma unroll
            for (int j = 0; j < 16; ++j) {
                int x = (int)(int8_t)(wb[j] >> (8 * b));
                int tt = x + cb;                 // <= 8 (x <= prefix max)
                s += (tt >= 0) ? (1 << tt) : 0;
            }
            esum[(qq * 4 + b) * 132 + g] = s;
        }
    }
    __syncthreads();

    // ---- Phase B4: sequential E recurrence (order-dependent, exact) ----
    if (t < 16) {
        int E = 0, Mp = -128;
        for (int g = 0; g < 128; ++g) {
            int m = gmax[t * 132 + g];
            int d = m - Mp; if (d > 31) d = 31;
            E = (E >> d) + esum[t * 132 + g];
            Mp = m;
        }
        invq[t] = 65280 / E;                     // E >= 256 -> inv <= 255
        gmq[t] = Mp;
    }
    __syncthreads();

    // ---- Phase T: in-place logits -> (attn - 128), once per byte ----
    {
        const int qw = t & 3;
        const int k15 = (t >> 2) & 15;
        const int band = t >> 6;
        int c24[4]; unsigned invv[4];
#pragma unroll
        for (int b = 0; b < 4; ++b) {
            c24[b] = 24 - gmq[qw * 4 + b];
            invv[b] = (unsigned)invq[qw * 4 + b];
        }
        for (int j = 0; j < 32; ++j) {
            const int kt = band * 32 + j;
            const int idx = kt * 68 + qw * 16 + k15;
            const int w = Lp[idx];
            unsigned outw = 0;
#pragma unroll
            for (int b = 0; b < 4; ++b) {
                int x = (int)(int8_t)(w >> (8 * b));
                int t1 = x + c24[b];
                t1 = (t1 < 0) ? 0 : t1;          // attn = inv >> (M-x), 0 if sh>24
                unsigned a = (invv[b] << t1) >> 24;
                outw |= ((a - 128u) & 255u) << (8 * b);
            }
            Lp[idx] = (int)outw;
        }
    }
    __syncthreads();

    // ---- Phase C: ctx partial = (attn-128) . V via MFMA (waves split kc) ----
    const int sh8 = 8 * (l15 & 3);
    v4i accs[4] = {zero, zero, zero, zero};
    const int8_t* vtb = V8T + base;

    for (int kc = wid * 8; kc < wid * 8 + 8; ++kc) {
        const int* lp = &Lp[(kc * 4 + quad) * 68 + (l15 >> 2) * 16];
        v4i a;
#pragma unroll
        for (int r = 0; r < 4; ++r) {
            const int w0 = lp[4 * r + 0], w1 = lp[4 * r + 1];
            const int w2 = lp[4 * r + 2], w3 = lp[4 * r + 3];
            a[r] = (int)((((unsigned)w0 >> sh8) & 255u) |
                         ((((unsigned)w1 >> sh8) & 255u) << 8) |
                         ((((unsigned)w2 >> sh8) & 255u) << 16) |
                         ((((unsigned)w3 >> sh8) & 255u) << 24));
        }
        const int koff = kc * 64 + quad * 16;
        v4i b0 = *(const v4i*)(vtb + (size_t)(0 * 16 + l15) * NN + koff);
        v4i b1 = *(const v4i*)(vtb + (size_t)(1 * 16 + l15) * NN + koff);
        v4i b2 = *(const v4i*)(vtb + (size_t)(2 * 16 + l15) * NN + koff);
        v4i b3 = *(const v4i*)(vtb + (size_t)(3 * 16 + l15) * NN + koff);
        accs[0] = __builtin_amdgcn_mfma_i32_16x16x64_i8(a, b0, accs[0], 0, 0, 0);
        accs[1] = __builtin_amdgcn_mfma_i32_16x16x64_i8(a, b1, accs[1], 0, 0, 0);
        accs[2] = __builtin_amdgcn_mfma_i32_16x16x64_i8(a, b2, accs[2], 0, 0, 0);
        accs[3] = __builtin_amdgcn_mfma_i32_16x16x64_i8(a, b3, accs[3], 0, 0, 0);
    }
    __syncthreads();                     // stats[] dead -> reuse as reduction buf

    // ---- Cross-wave reduction + epilogue ----
    if (wid > 0) {
#pragma unroll
        for (int dt = 0; dt < 4; ++dt)
#pragma unroll
            for (int r = 0; r < 4; ++r)
                stats[(dt * 4 + r) * 192 + (wid - 1) * 64 + lane] = accs[dt][r];
    }
    __syncthreads();
    if (wid == 0) {
        const int bb = bh / NH, hh = bh % NH;
        const int* cs = &colsum[bh * 64];
#pragma unroll
        for (int dt = 0; dt < 4; ++dt) {
            const int dcol = dt * 16 + l15;
            const int corr = cs[dcol] << 7;      // +128 * colsum
#pragma unroll
            for (int r = 0; r < 4; ++r) {
                const int i = dt * 4 + r;
                int val = accs[dt][r]
                        + stats[i * 192 + 0 * 64 + lane]
                        + stats[i * 192 + 1 * 64 + lane]
                        + stats[i * 192 + 2 * 64 + lane];
                const int q = q0 + quad * 4 + r;
                val = (val + corr) >> 8;         // MAV=1, SAV=8 floor
                val = min(127, max(-128, val));
                CTX8[((size_t)(bb * NN + q)) * ND + hh * HD + dcol] = (int8_t)val;
            }
        }
    }
}

// ---------------------------------------------------------------------------
// Kernel 3: out = requantize(ctx @ wo^T + bo, 256, 7) -> floor(v*2), clamp
// ---------------------------------------------------------------------------
__global__ __launch_bounds__(256) void out_gemm_kernel(
    const int8_t* __restrict__ CTX8, const float* __restrict__ Wo,
    const float* __restrict__ Bo, float* __restrict__ out)
{
    __shared__ float As[16][68];
    __shared__ float Bs[16][68];

    const int t = threadIdx.x;
    const int row0 = blockIdx.x * 64;
    const int c0 = blockIdx.y * 64;
    const int li = t >> 2;
    const int lk = (t & 3) << 2;
    const int tx = t & 15, ty = t >> 4;

    float acc[4][4] = {{0.f}};

    for (int k0 = 0; k0 < ND; k0 += 16) {
        const int av = *(const int*)&CTX8[(size_t)(row0 + li) * ND + k0 + lk];
        float4 b = *(const float4*)&Wo[(size_t)(c0 + li) * ND + k0 + lk];
        As[lk + 0][li] = (float)(int)(int8_t)(av & 0xFF);
        As[lk + 1][li] = (float)(int)(int8_t)((av >> 8) & 0xFF);
        As[lk + 2][li] = (float)(int)(int8_t)((av >> 16) & 0xFF);
        As[lk + 3][li] = (float)(int)(int8_t)((av >> 24) & 0xFF);
        Bs[lk + 0][li] = b.x; Bs[lk + 1][li] = b.y; Bs[lk + 2][li] = b.z; Bs[lk + 3][li] = b.w;
        __syncthreads();
#pragma unroll
        for (int kk = 0; kk < 16; kk++) {
            float4 avv = *(const float4*)&As[kk][ty * 4];
            float4 bvv = *(const float4*)&Bs[kk][tx * 4];
            float aa[4] = {avv.x, avv.y, avv.z, avv.w};
            float bb[4] = {bvv.x, bvv.y, bvv.z, bvv.w};
#pragma unroll
            for (int i = 0; i < 4; i++)
#pragma unroll
                for (int j = 0; j < 4; j++)
                    acc[i][j] += aa[i] * bb[j];
        }
        __syncthreads();
    }

#pragma unroll
    for (int i = 0; i < 4; i++) {
        const int r = row0 + ty * 4 + i;
#pragma unroll
        for (int j = 0; j < 4; j++) {
            const int c = c0 + tx * 4 + j;
            float v = acc[i][j] + Bo[c];
            float rq = floorf(v * 2.0f);
            rq = fminf(fmaxf(rq, -128.0f), 127.0f);
            out[(size_t)r * ND + c] = rq;
        }
    }
}

extern "C" void kernel_launch(void* const* d_in, const int* in_sizes, int n_in,
                              void* d_out, int out_size, void* d_ws, size_t ws_size,
                              hipStream_t stream)
{
    const float* x  = (const float*)d_in[0];
    const float* wq = (const float*)d_in[1];
    const float* bq = (const float*)d_in[2];
    const float* wk = (const float*)d_in[3];
    const float* bk = (const float*)d_in[4];
    const float* wv = (const float*)d_in[5];
    const float* bv = (const float*)d_in[6];
    const float* wo = (const float*)d_in[7];
    const float* bo = (const float*)d_in[8];
    float* out = (float*)d_out;

    const size_t MAT = (size_t)ROWS * ND;
    int8_t* Q8  = (int8_t*)d_ws;
    int8_t* K8  = Q8 + MAT;
    int8_t* V8T = K8 + MAT;
    int8_t* C8  = V8T + MAT;
    int*    CS  = (int*)(C8 + MAT);

    qkv_gemm_kernel<<<dim3(ROWS / 64, 18), 256, 0, stream>>>(
        x, wq, wk, wv, bq, bk, bv, Q8, K8, V8T);
    colsum_kernel<<<dim3(NB * NH), 256, 0, stream>>>(V8T, CS);
    attn_kernel<<<dim3(NN / 16, NB * NH), 256, 0, stream>>>(Q8, K8, V8T, CS, C8);
    out_gemm_kernel<<<dim3(ROWS / 64, ND / 64), 256, 0, stream>>>(C8, wo, bo, out);
}